// Round 8
// baseline (45.153 us; speedup 1.0000x reference)
//
#include <hip/hip_runtime.h>
#include <hip/hip_bf16.h>

#define UNITS 64
#define IFEAT 256
#define OFEAT 256

typedef __attribute__((ext_vector_type(8))) short v8s;   // 8 bf16 (4 VGPRs)
typedef __attribute__((ext_vector_type(4))) float v4f;   // MFMA acc / global f32x4

// pack 2 floats -> u32 of 2 bf16 (RNE) — compiler emits v_cvt_pk_bf16_f32
static __device__ __forceinline__ unsigned int pk2(float a, float b) {
    union { __hip_bfloat162 h; unsigned int u; } c;
    c.h = __float22bfloat162_rn(float2{a, b});
    return c.u;
}

static __device__ __forceinline__ float sigmoid_f(float x) {
    return 1.0f / (1.0f + __expf(-x));
}
static __device__ __forceinline__ float tanh_f(float x) {
    float ax = fabsf(x);
    float e = __expf(-2.0f * ax);
    float t = (1.0f - e) / (1.0f + e);
    return copysignf(t, x);
}

// ---------------------------------------------------------------------------
// Single fused kernel: per-unit 3-way MFMA GEMM + in-block hvec + GRU epilogue.
// BM=128, BN=128, BK=32. 1024 threads = 16 waves (4m x 4n), wave tile 32x32.
// A (x tile) full-K resident in LDS (64KB, rotated conflict-free layout).
// B (W_i) double-buffered per K-step (register-transpose, conflict-free b128).
// hvec = hinit . w_h computed in-block during the prologue: 393KB w_h slice
// streamed (coalesced) into per-i-chunk LDS partials, reduced at K-step 1,
// consumed from LDS in the epilogue. The w_h slice is shared by the mb=0/1
// twin block on the same XCD -> HBM reads it once, L2 serves the twin.
// LDS 125.5KB -> 1 block/CU; grid 256 = 64u x 2mb x 2nb = exactly 1/CU.
// ---------------------------------------------------------------------------
__global__ __launch_bounds__(1024, 4) void gru_fused(
    const float* __restrict__ x,
    const float* __restrict__ wir,
    const float* __restrict__ wiz,
    const float* __restrict__ win,
    const float* __restrict__ whr,
    const float* __restrict__ whz,
    const float* __restrict__ whn,
    const float* __restrict__ hinit,
    float* __restrict__ out) {
    __shared__ unsigned short As[32][128][8];        // [kq][row'][j]        64 KB
    __shared__ unsigned short Bs[2][3][4][128][8];   // [buf][g][kq][col][j] 48 KB
    __shared__ float Ph[8][3][128];                  // hvec partials        12 KB
    __shared__ float Hf[3][128];                     // hvec final          1.5 KB

    const int bid = blockIdx.x;
    // XCD swizzle: xcd = bid&7 owns units [xcd*8, xcd*8+8); 4 blocks/unit.
    const int idx = bid >> 3;                  // 0..31 within XCD
    const int u   = (bid & 7) * 8 + (idx >> 2);
    const int rem = idx & 3;
    const int b0  = (rem >> 1) * 128;          // batch tile 0..1
    const int o0  = (rem & 1) * 128;           // out-feature tile 0..1

    const int t    = threadIdx.x;
    const int lane = t & 63;
    const int wv   = t >> 6;                   // 16 waves: 4m x 4n
    const int wm   = wv >> 2;                  // 0..3
    const int wn   = wv & 3;                   // 0..3
    const int lg   = lane >> 4;                // k-quad within step
    const int lr   = lane & 15;

    // ---- B staging: 1536 col-vectors/step over 1024 threads ----
    const int bcol = t & 127;
    const int bkq  = (t >> 7) & 3;
    const int gA   = t >> 9;                   // wave-uniform (0 or 1)
    const bool hasB = (wv < 8);                // wave-uniform
    const float* wpA = (gA == 0) ? wir : wiz;
    const size_t bgbase = (size_t)u * (IFEAT * OFEAT) + (bkq * 8) * OFEAT + o0 + bcol;

    float rbA[8], rbB[8];

    auto bload = [&](int kk) {
        const size_t off = bgbase + (size_t)kk * 32 * OFEAT;
#pragma unroll
        for (int j = 0; j < 8; ++j) rbA[j] = wpA[off + j * OFEAT];
        if (hasB) {
#pragma unroll
            for (int j = 0; j < 8; ++j) rbB[j] = win[off + j * OFEAT];
        }
    };
    auto bwrite = [&](int bb) {
        uint4 v;
        v.x = pk2(rbA[0], rbA[1]);
        v.y = pk2(rbA[2], rbA[3]);
        v.z = pk2(rbA[4], rbA[5]);
        v.w = pk2(rbA[6], rbA[7]);
        *(uint4*)&Bs[bb][gA][bkq][bcol][0] = v;
        if (hasB) {
            uint4 w;
            w.x = pk2(rbB[0], rbB[1]);
            w.y = pk2(rbB[2], rbB[3]);
            w.z = pk2(rbB[4], rbB[5]);
            w.w = pk2(rbB[6], rbB[7]);
            *(uint4*)&Bs[bb][2][bkq][bcol][0] = w;
        }
    };

    v4f acc[3][2][2];
#pragma unroll
    for (int g = 0; g < 3; ++g)
#pragma unroll
        for (int mi = 0; mi < 2; ++mi)
#pragma unroll
            for (int ni = 0; ni < 2; ++ni)
                acc[g][mi][ni] = (v4f){0.f, 0.f, 0.f, 0.f};

    // ---- prologue ----
    bload(0);                                  // B(0) in flight
    {
        // A-tile: rows coalesced (1KB row per instr), rotated frag layout
        const int kqA = lane >> 1;             // lane owns k = lane*4..+3
        const int j0  = (lane & 1) * 4;
#pragma unroll
        for (int i = 0; i < 8; ++i) {
            const int row = wv * 8 + i;
            v4f q = *(const v4f*)(x + (size_t)(b0 + row) * (UNITS * IFEAT)
                                    + u * IFEAT + lane * 4);
            uint2 w;
            w.x = pk2(q[0], q[1]);
            w.y = pk2(q[2], q[3]);
            *(uint2*)&As[kqA][(row + kqA) & 127][j0] = w;
        }
    }
    bwrite(0);
    bload(1);                                  // B(1) flies during hvec

    // ---- fused hvec: Ph[q][g][o] = sum_{i in chunk q} hinit[u,i]*w_h[u,i,o0+o]
    {
        const int ho = t & 127;                // o-col within slice
        const int hq = t >> 7;                 // i-chunk 0..7 (wave-uniform)
        const float* hp = hinit + u * IFEAT + hq * 32;
        const size_t whbase = (size_t)u * (IFEAT * OFEAT)
                            + (size_t)(hq * 32) * OFEAT + o0 + ho;
        float p0 = 0.f, p1 = 0.f, p2 = 0.f;
#pragma unroll
        for (int i = 0; i < 32; ++i) {
            const float hi = hp[i];            // wave-uniform -> scalar load
            const size_t off = whbase + (size_t)i * OFEAT;
            p0 += hi * whr[off];
            p1 += hi * whz[off];
            p2 += hi * whn[off];
        }
        Ph[hq][0][ho] = p0;
        Ph[hq][1][ho] = p1;
        Ph[hq][2][ho] = p2;
    }

    __syncthreads();

    // ---- K-loop: 8 steps, dbuf B, 1 barrier/step ----
#pragma unroll
    for (int kk = 0; kk < 8; ++kk) {
        const int bb = kk & 1;
        if (kk == 1 && t < 384) {
            // hvec reduce (after barrier 1; Hf ordered before epilogue by
            // barriers 2..7). 384 threads, conflict-free stride-1 reads.
            const int g = t >> 7, o = t & 127;
            float s = 0.f;
#pragma unroll
            for (int q = 0; q < 8; ++q) s += Ph[q][g][o];
            Hf[g][o] = s;
        }
        if (kk < 7) bwrite(bb ^ 1);        // data for kk+1 into other buffer
        if (kk < 6) bload(kk + 2);         // refill regs; lands under MFMAs

        const int kq0 = kk * 4 + lg;
        v8s a0 = *(const v8s*)&As[kq0][((wm * 32 + lr) + kq0) & 127][0];
        v8s a1 = *(const v8s*)&As[kq0][((wm * 32 + 16 + lr) + kq0) & 127][0];
#pragma unroll
        for (int g = 0; g < 3; ++g) {
#pragma unroll
            for (int ni = 0; ni < 2; ++ni) {
                v8s b = *(const v8s*)&Bs[bb][g][lg][wn * 32 + ni * 16 + lr][0];
                acc[g][0][ni] = __builtin_amdgcn_mfma_f32_16x16x32_bf16(a0, b, acc[g][0][ni], 0, 0, 0);
                acc[g][1][ni] = __builtin_amdgcn_mfma_f32_16x16x32_bf16(a1, b, acc[g][1][ni], 0, 0, 0);
            }
        }
        if (kk < 7) __syncthreads();       // writes(bb^1) visible, reads(bb) done
    }

    // ---- epilogue: GRU combine (hvec from LDS) ----
    // C layout: col = lane&15, row = (lane>>4)*4 + reg
    float hrv[2], hzv[2], hnv[2], h0v[2];
#pragma unroll
    for (int ni = 0; ni < 2; ++ni) {
        const int ol = wn * 32 + ni * 16 + lr;     // o within slice
        hrv[ni] = Hf[0][ol];
        hzv[ni] = Hf[1][ol];
        hnv[ni] = Hf[2][ol];
        h0v[ni] = hinit[u * OFEAT + o0 + ol];
    }
    const int obase = o0 + wn * 32 + lr;
    const int rbase = b0 + wm * 32 + lg * 4;
#pragma unroll
    for (int mi = 0; mi < 2; ++mi) {
#pragma unroll
        for (int ni = 0; ni < 2; ++ni) {
            const int o = obase + ni * 16;
#pragma unroll
            for (int jj = 0; jj < 4; ++jj) {
                const int row = rbase + mi * 16 + jj;
                const float r = sigmoid_f(acc[0][mi][ni][jj] + hrv[ni]);
                const float z = sigmoid_f(acc[1][mi][ni][jj] + hzv[ni]);
                const float n = tanh_f(acc[2][mi][ni][jj] + r * hnv[ni]);
                out[((size_t)row * UNITS + u) * OFEAT + o] = (1.0f - z) * n + z * h0v[ni];
            }
        }
    }
}

extern "C" void kernel_launch(void* const* d_in, const int* in_sizes, int n_in,
                              void* d_out, int out_size, void* d_ws, size_t ws_size,
                              hipStream_t stream) {
    const float* x     = (const float*)d_in[0];
    const float* w_ir  = (const float*)d_in[1];
    const float* w_iz  = (const float*)d_in[2];
    const float* w_in  = (const float*)d_in[3];
    const float* w_hr  = (const float*)d_in[4];
    const float* w_hz  = (const float*)d_in[5];
    const float* w_hn  = (const float*)d_in[6];
    const float* hinit = (const float*)d_in[7];
    float* out = (float*)d_out;

    gru_fused<<<dim3(256), dim3(1024), 0, stream>>>(
        x, w_ir, w_iz, w_in, w_hr, w_hz, w_hn, hinit, out);
}